// Round 17
// baseline (314.998 us; speedup 1.0000x reference)
//
#include <hip/hip_runtime.h>

// ---------------------------------------------------------------------------
// Fused equivariant FFN, bf16 MFMA (16x16x32), fp32 accumulate.
// Round 17 = Round 16 EXACT (314.6us best) + ONE change: s_setprio(1)/(0)
// around every MFMA cluster (T5). Mechanism: 2 independent blocks/CU at
// different phases + intra-block GEMM-vs-staging wave role split -> priority
// hint lets MFMA-issuing waves win CU issue arbitration over memory-phase
// waves. Pure scheduler hint: zero addressing/layout/barrier changes.
// Session rules: (512,4) only; no X-register hoisting across Phase A;
// weight frags prefetched behind barriers and reused.
// ---------------------------------------------------------------------------

typedef __attribute__((ext_vector_type(8))) short short8;   // 8 bf16 = 4 VGPRs
typedef __attribute__((ext_vector_type(4))) float f32x4;

#define INV_M0f 0.08838834764831845f   // 1/sqrt(128)
#define INV_M1f 0.125f                 // 1/sqrt(64)
#define INV_M2f 0.17677669529663687f   // 1/sqrt(32)
#define INV_H0f 0.05103103630798288f   // 1/sqrt(384)
#define INV_H1f 0.07216878364870323f   // 1/sqrt(192)
#define INV_H2f 0.10206207261596577f   // 1/sqrt(96)

// packed bf16 weight offsets inside d_ws (units: shorts), pre-scaled by INV_*
#define OFF_W0T 0         // [672][128]  (W0s|W0g)^T * INV_M0
#define OFF_W1T 86016     // [192][64]   W1^T * INV_M1
#define OFF_W2T 98304     // [96][32]    W2^T * INV_M2
#define OFF_V0T 101376    // [128][384]  V0^T * INV_H0
#define OFF_V1T 150528    // [64][192]   V1^T * INV_H1
#define OFF_V2T 162816    // [32][96]    V2^T * INV_H2
#define WP_TOTAL 165888

__device__ __forceinline__ short f2bf_rne(float f) {        // prep only
    union { float f; unsigned u; } v; v.f = f;
    unsigned r = v.u + 0x7FFFu + ((v.u >> 16) & 1u);
    return (short)(r >> 16);
}
// 1-VALU bf16 convert (RNE) for the hot kernel
__device__ __forceinline__ short f2bf_fast(float f) {
    unsigned r;
    asm("v_cvt_pk_bf16_f32 %0, %1, %1" : "=v"(r) : "v"(f));
    return (short)r;
}
__device__ __forceinline__ float bf2f(short s) {
    union { unsigned u; float f; } v; v.u = ((unsigned)(unsigned short)s) << 16;
    return v.f;
}

__global__ void prep_weights(const float* __restrict__ W0s, const float* __restrict__ W0g,
                             const float* __restrict__ W1,  const float* __restrict__ W2,
                             const float* __restrict__ V0,  const float* __restrict__ V1,
                             const float* __restrict__ V2,  short* __restrict__ ws)
{
    int i = blockIdx.x * 256 + threadIdx.x;
    if (i < 86016) {                    // W0T [672][128]
        int j = i >> 7, k = i & 127;
        float v = (j < 384) ? W0s[k * 384 + j] : W0g[k * 288 + (j - 384)];
        ws[i] = f2bf_rne(v * INV_M0f);
    } else if (i < 98304) {             // W1T [192][64]
        int e = i - 86016; int w = e >> 6, u = e & 63;
        ws[i] = f2bf_rne(W1[u * 192 + w] * INV_M1f);
    } else if (i < 101376) {            // W2T [96][32]
        int e = i - 98304; int w = e >> 5, u = e & 31;
        ws[i] = f2bf_rne(W2[u * 96 + w] * INV_M2f);
    } else if (i < 150528) {            // V0T [128][384]
        int e = i - 101376; int j = e / 384, w = e % 384;
        ws[i] = f2bf_rne(V0[w * 128 + j] * INV_H0f);
    } else if (i < 162816) {            // V1T [64][192]
        int e = i - 150528; int j = e / 192, w = e % 192;
        ws[i] = f2bf_rne(V1[w * 64 + j] * INV_H1f);
    } else if (i < WP_TOTAL) {          // V2T [32][96]
        int e = i - 162816; int j = e / 96, w = e % 96;
        ws[i] = f2bf_rne(V2[w * 32 + j] * INV_H2f);
    }
}

// ---- LDS layout (shorts), total 36480 shorts = 72960 B ----
// x0s   @     0 : [32][136] = 4352     (start -> end Phase A)
// sbuf  @  4352 : [32][392] = 12544    (Phase A -> Phase D)  [4352,16896)
// gT    @ 26112 : [288][36] = 10368    (Phase A -> end)      [26112,36480)
// x1T   @     0 : [3][32][72] = 6912   (after D; dead x0s+sbuf head)
// ubuf1 @  6912 : [3][32][200] = 19200 (B1 planes)           [6912,26112)
// x2T   @     0 : [5][32][40] = 6400   (staged during B1-G2; dead x1T)
// ubuf2 @  6400 : [5][32][104] = 16640 (B2 planes)           [6400,23040)
#define X0_STRIDE 136
#define SB_OFF 4352
#define SB_STRIDE 392
#define GT_OFF 26112
#define GT_STRIDE 36
#define UB1_OFF 6912
#define UB1_PLANE 6400
#define UB1_STRIDE 200
#define UB2_OFF 6400
#define UB2_PLANE 3328
#define UB2_STRIDE 104
#define LDS_SHORTS 36480

#define MFMA(a, b, c) __builtin_amdgcn_mfma_f32_16x16x32_bf16((a), (b), (c), 0, 0, 0)
#define PRIO_HI() __builtin_amdgcn_s_setprio(1)
#define PRIO_LO() __builtin_amdgcn_s_setprio(0)

__global__ __launch_bounds__(512, 4) void ffn_main(
    const float* __restrict__ X, const float* __restrict__ Y,
    const float* __restrict__ bs, const float* __restrict__ bg, const float* __restrict__ bo,
    const short* __restrict__ WP, float* __restrict__ out)
{
    __shared__ short lds[LDS_SHORTS];
    short* x0s   = lds;
    short* sbuf  = lds + SB_OFF;
    short* gT    = lds + GT_OFF;
    short* x1T   = lds;
    short* x2T   = lds;
    short* ubuf1 = lds + UB1_OFF;
    short* ubuf2 = lds + UB2_OFF;

    const int tid  = threadIdx.x;
    const int wid  = tid >> 6;     // wave 0..7
    const int lane = tid & 63;
    const int m    = lane & 15;    // A-row(node) / B-row(out-col) index
    const int bq   = lane >> 4;    // k-block; D row-group
    const int n0   = blockIdx.x * 32;

    // ---- prefetch Phase-A weight tiles 0 and 1 (depth-2 pipeline) ----
    short8 w0c[4], w0n[4];
    float bias_c, bias_n;
    {
        const short* w = WP + OFF_W0T + (wid * 16 + m) * 128 + bq * 8;
        #pragma unroll
        for (int k = 0; k < 4; ++k) w0c[k] = *(const short8*)(w + k * 32);
        bias_c = bs[wid * 16 + m];
        const short* w2 = WP + OFF_W0T + ((wid + 8) * 16 + m) * 128 + bq * 8;
        #pragma unroll
        for (int k = 0; k < 4; ++k) w0n[k] = *(const short8*)(w2 + k * 32);
        bias_n = bs[(wid + 8) * 16 + m];
    }

    // ---- stage x0 (32 nodes x 128 cols) -> LDS bf16, coalesced ----
    {
        const int node = tid >> 4, c16 = tid & 15;
        const float* xp = X + (size_t)(n0 + node) * 480 + c16 * 8;
        float4 f0 = *(const float4*)xp;
        float4 f1 = *(const float4*)(xp + 4);
        short8 a;
        a[0]=f2bf_fast(f0.x); a[1]=f2bf_fast(f0.y); a[2]=f2bf_fast(f0.z); a[3]=f2bf_fast(f0.w);
        a[4]=f2bf_fast(f1.x); a[5]=f2bf_fast(f1.y); a[6]=f2bf_fast(f1.z); a[7]=f2bf_fast(f1.w);
        *(short8*)(x0s + node * X0_STRIDE + c16 * 8) = a;
    }

    // y for the 8 output rows this lane touches: rows t*16 + bq*4 + r
    float yv[2][4];
    #pragma unroll
    for (int t = 0; t < 2; ++t)
        #pragma unroll
        for (int r = 0; r < 4; ++r)
            yv[t][r] = Y[n0 + t * 16 + bq * 4 + r];

    __syncthreads();                                        // [b1]

    // x0 A-fragments, both row-tiles
    short8 a0[2][4];
    #pragma unroll
    for (int t = 0; t < 2; ++t)
        #pragma unroll
        for (int k = 0; k < 4; ++k)
            a0[t][k] = *(const short8*)(x0s + (t * 16 + m) * X0_STRIDE + k * 32 + bq * 8);

    // ---- Phase A: pre(32x672) = x0 @ W0T^T ; s -> sbuf, g -> gT ----
    // jt = wid + 8i, depth-2 software pipeline (tile i+2 in flight)
    #pragma unroll 1
    for (int i = 0; i < 6; ++i) {
        const int jt = wid + i * 8;
        if (jt >= 42) break;
        const int jnn = jt + 16;
        short8 w0nn[4];
        float bias_nn = 0.f;
        if (jnn < 42) {
            const short* w = WP + OFF_W0T + (jnn * 16 + m) * 128 + bq * 8;
            #pragma unroll
            for (int k = 0; k < 4; ++k) w0nn[k] = *(const short8*)(w + k * 32);
            bias_nn = (jnn < 24) ? bs[jnn * 16 + m] : bg[(jnn - 24) * 16 + m];
        }
        f32x4 acc0 = {0.f,0.f,0.f,0.f}, acc1 = {0.f,0.f,0.f,0.f};
        PRIO_HI();
        #pragma unroll
        for (int k = 0; k < 4; ++k) {
            acc0 = MFMA(a0[0][k], w0c[k], acc0);
            acc1 = MFMA(a0[1][k], w0c[k], acc1);
        }
        PRIO_LO();
        if (jt < 24) {          // silu -> sbuf, col j = jt*16+m
            #pragma unroll
            for (int t = 0; t < 2; ++t) {
                f32x4 acc = t ? acc1 : acc0;
                #pragma unroll
                for (int r = 0; r < 4; ++r) {
                    float val = fmaf(acc[r], yv[t][r], bias_c);
                    float e   = __expf(-val);
                    float sv  = val * __builtin_amdgcn_rcpf(1.f + e);
                    sbuf[(t * 16 + bq * 4 + r) * SB_STRIDE + jt * 16 + m] = f2bf_fast(sv);
                }
            }
        } else {                // sigmoid -> gT[w][node], short4 over r
            const int w = (jt - 24) * 16 + m;
            #pragma unroll
            for (int t = 0; t < 2; ++t) {
                f32x4 acc = t ? acc1 : acc0;
                float sg[4];
                #pragma unroll
                for (int r = 0; r < 4; ++r) {
                    float val = fmaf(acc[r], yv[t][r], bias_c);
                    float e   = __expf(-val);
                    sg[r] = __builtin_amdgcn_rcpf(1.f + e);
                }
                short4 pk;
                pk.x = f2bf_fast(sg[0]); pk.y = f2bf_fast(sg[1]);
                pk.z = f2bf_fast(sg[2]); pk.w = f2bf_fast(sg[3]);
                *(short4*)(gT + w * GT_STRIDE + t * 16 + bq * 4) = pk;
            }
        }
        #pragma unroll
        for (int k = 0; k < 4; ++k) { w0c[k] = w0n[k]; w0n[k] = w0nn[k]; }
        bias_c = bias_n;
        bias_n = bias_nn;
    }

    // ---- prefetch Phase-D weights (V0T) + bias before the barrier ----
    short8 v0f[12];
    {
        const short* v = WP + OFF_V0T + (wid * 16 + m) * 384 + bq * 8;
        #pragma unroll
        for (int k = 0; k < 12; ++k) v0f[k] = *(const short8*)(v + k * 32);
    }
    const float bo_r = bo[wid * 16 + m];
    __syncthreads();                                        // [b2]

    // ---- Phase D: o0(32x128) = s @ V0 ; 1 j-tile per wave ----
    {
        f32x4 accD0 = {0.f,0.f,0.f,0.f}, accD1 = {0.f,0.f,0.f,0.f};
        PRIO_HI();
        #pragma unroll
        for (int k = 0; k < 12; ++k) {
            short8 sa0 = *(const short8*)(sbuf + m * SB_STRIDE + k * 32 + bq * 8);
            short8 sa1 = *(const short8*)(sbuf + (16 + m) * SB_STRIDE + k * 32 + bq * 8);
            accD0 = MFMA(sa0, v0f[k], accD0);
            accD1 = MFMA(sa1, v0f[k], accD1);
        }
        PRIO_LO();
        #pragma unroll
        for (int t = 0; t < 2; ++t) {
            f32x4 acc = t ? accD1 : accD0;
            #pragma unroll
            for (int r = 0; r < 4; ++r)
                out[(size_t)(n0 + t * 16 + bq * 4 + r) * 480 + wid * 16 + m] =
                    fmaf(acc[r], yv[t][r], bo_r);
        }
    }

    // ---- prefetch B1 + B2 weights while D's sbuf reads drain ----
    short8 w1f[2][2];                   // [jj][k4], jt = wid + jj*8 (<12)
    #pragma unroll
    for (int jj = 0; jj < 2; ++jj) {
        const int jt = wid + jj * 8;
        if (jt < 12) {
            const short* w = WP + OFF_W1T + (jt * 16 + m) * 64 + bq * 8;
            w1f[jj][0] = *(const short8*)(w);
            w1f[jj][1] = *(const short8*)(w + 32);
        }
    }
    short8 v1f[6];                      // waves 4..7: V1T j-tile (wid-4)
    if (wid >= 4) {
        const short* v = WP + OFF_V1T + ((wid - 4) * 16 + m) * 192 + bq * 8;
        #pragma unroll
        for (int k = 0; k < 6; ++k) v1f[k] = *(const short8*)(v + k * 32);
    }
    short8 w2f;                          // waves 0..5: W2T j-tile wid
    if (wid < 6)
        w2f = *(const short8*)(WP + OFF_W2T + (wid * 16 + m) * 32 + bq * 8);
    short8 v2f[3];                       // waves 6..7: V2T j-tile (wid-6)
    if (wid >= 6) {
        const short* v = WP + OFF_V2T + ((wid - 6) * 16 + m) * 96 + bq * 8;
        #pragma unroll
        for (int k = 0; k < 3; ++k) v2f[k] = *(const short8*)(v + k * 32);
    }
    __syncthreads();   // [b3] sbuf reads done; x1T region may be written

    // ---- stage x1 transposed: x1T[mm][node][u]; short4-wide writes ----
    {
        const int node = tid >> 4, c16 = tid & 15;
        const float* xp = X + (size_t)(n0 + node) * 480 + 128 + c16 * 12;
        float4 fa = *(const float4*)xp;
        float4 fb = *(const float4*)(xp + 4);
        float4 fc = *(const float4*)(xp + 8);
        float vals[12] = {fa.x,fa.y,fa.z,fa.w, fb.x,fb.y,fb.z,fb.w, fc.x,fc.y,fc.z,fc.w};
        #pragma unroll
        for (int mmv = 0; mmv < 3; ++mmv) {
            short4 s4;
            s4.x = f2bf_fast(vals[mmv]);
            s4.y = f2bf_fast(vals[mmv + 3]);
            s4.z = f2bf_fast(vals[mmv + 6]);
            s4.w = f2bf_fast(vals[mmv + 9]);
            *(short4*)(x1T + mmv * 2304 + node * 72 + c16 * 4) = s4;
        }
    }
    __syncthreads();                                        // [b4]

    // ---- B1-GEMM1, ALL 3 mm back-to-back into per-mm planes ----
    #pragma unroll
    for (int mm = 0; mm < 3; ++mm) {
        #pragma unroll
        for (int jj = 0; jj < 2; ++jj) {
            const int jt = wid + jj * 8;
            if (jt < 12) {
                f32x4 accA = {0.f,0.f,0.f,0.f}, accB = {0.f,0.f,0.f,0.f};
                short8 a00 = *(const short8*)(x1T + mm * 2304 + m * 72 + bq * 8);
                short8 a01 = *(const short8*)(x1T + mm * 2304 + m * 72 + 32 + bq * 8);
                short8 a10 = *(const short8*)(x1T + mm * 2304 + (16 + m) * 72 + bq * 8);
                short8 a11 = *(const short8*)(x1T + mm * 2304 + (16 + m) * 72 + 32 + bq * 8);
                PRIO_HI();
                accA = MFMA(a00, w1f[jj][0], accA);
                accA = MFMA(a01, w1f[jj][1], accA);
                accB = MFMA(a10, w1f[jj][0], accB);
                accB = MFMA(a11, w1f[jj][1], accB);
                PRIO_LO();
                const int w = jt * 16 + m;
                #pragma unroll
                for (int t = 0; t < 2; ++t) {
                    f32x4 acc = t ? accB : accA;
                    short4 g4 = *(const short4*)(gT + w * GT_STRIDE + t * 16 + bq * 4);
                    #pragma unroll
                    for (int r = 0; r < 4; ++r) {
                        const int node = t * 16 + bq * 4 + r;
                        float gv = bf2f(r == 0 ? g4.x : r == 1 ? g4.y : r == 2 ? g4.z : g4.w);
                        ubuf1[mm * UB1_PLANE + node * UB1_STRIDE + w] =
                            f2bf_fast(acc[r] * yv[t][r] * gv);
                    }
                }
            }
        }
    }
    __syncthreads();   // [b5] all v1 planes ready; x1T dead

    // ---- B1-GEMM2 (waves 4-7, all 3 mm) || x2T staging (waves 0-3) ----
    if (wid >= 4) {
        float o1a[3][2][4];
        PRIO_HI();
        #pragma unroll
        for (int mm = 0; mm < 3; ++mm) {
            f32x4 accA = {0.f,0.f,0.f,0.f}, accB = {0.f,0.f,0.f,0.f};
            #pragma unroll
            for (int k = 0; k < 6; ++k) {
                short8 au0 = *(const short8*)(ubuf1 + mm * UB1_PLANE + m * UB1_STRIDE + k * 32 + bq * 8);
                short8 au1 = *(const short8*)(ubuf1 + mm * UB1_PLANE + (16 + m) * UB1_STRIDE + k * 32 + bq * 8);
                accA = MFMA(au0, v1f[k], accA);
                accB = MFMA(au1, v1f[k], accB);
            }
            #pragma unroll
            for (int t = 0; t < 2; ++t) {
                f32x4 acc = t ? accB : accA;
                #pragma unroll
                for (int r = 0; r < 4; ++r)
                    o1a[mm][t][r] = acc[r] * yv[t][r];
            }
        }
        PRIO_LO();
        // dense o1 stores: 12B contiguous per lane per row
        const int jc = (wid - 4) * 16 + m;
        #pragma unroll
        for (int t = 0; t < 2; ++t)
            #pragma unroll
            for (int r = 0; r < 4; ++r) {
                float* p = out + (size_t)(n0 + t * 16 + bq * 4 + r) * 480 + 128 + jc * 3;
                p[0] = o1a[0][t][r]; p[1] = o1a[1][t][r]; p[2] = o1a[2][t][r];
            }
    } else {
        // x2T [mm][node][u] staged by 256 threads: node = tid>>3, 20 cols each
        const int node2 = tid >> 3;          // 0..31
        const int c8 = tid & 7;
        const float* xp2 = X + (size_t)(n0 + node2) * 480 + 320 + c8 * 20;
        float vals[20];
        #pragma unroll
        for (int p = 0; p < 5; ++p) {
            float4 f = *(const float4*)(xp2 + p * 4);
            vals[p * 4] = f.x; vals[p * 4 + 1] = f.y;
            vals[p * 4 + 2] = f.z; vals[p * 4 + 3] = f.w;
        }
        // col = c8*20 + c -> mm = c%5, u = c8*4 + c/5 ; per mm 4 consecutive u
        #pragma unroll
        for (int mmv = 0; mmv < 5; ++mmv) {
            short4 s4;
            s4.x = f2bf_fast(vals[mmv]);
            s4.y = f2bf_fast(vals[mmv + 5]);
            s4.z = f2bf_fast(vals[mmv + 10]);
            s4.w = f2bf_fast(vals[mmv + 15]);
            *(short4*)(x2T + mmv * 1280 + node2 * 40 + c8 * 4) = s4;
        }
    }
    __syncthreads();   // [b6] x2T ready; ubuf1 reads done (ubuf2 overlays it)

    // ---- B2-GEMM1, ALL 5 mm back-to-back into per-mm planes (waves 0-5) ----
    if (wid < 6) {
        #pragma unroll
        for (int mm = 0; mm < 5; ++mm) {
            f32x4 zz = {0.f,0.f,0.f,0.f};
            short8 a20 = *(const short8*)(x2T + mm * 1280 + m * 40 + bq * 8);
            short8 a21 = *(const short8*)(x2T + mm * 1280 + (16 + m) * 40 + bq * 8);
            PRIO_HI();
            f32x4 accA = MFMA(a20, w2f, zz);
            f32x4 accB = MFMA(a21, w2f, zz);
            PRIO_LO();
            const int w = 192 + wid * 16 + m;
            #pragma unroll
            for (int t = 0; t < 2; ++t) {
                f32x4 acc = t ? accB : accA;
                short4 g4 = *(const short4*)(gT + w * GT_STRIDE + t * 16 + bq * 4);
                #pragma unroll
                for (int r = 0; r < 4; ++r) {
                    const int node = t * 16 + bq * 4 + r;
                    float gv = bf2f(r == 0 ? g4.x : r == 1 ? g4.y : r == 2 ? g4.z : g4.w);
                    ubuf2[mm * UB2_PLANE + node * UB2_STRIDE + wid * 16 + m] =
                        f2bf_fast(acc[r] * yv[t][r] * gv);
                }
            }
        }
    }
    __syncthreads();   // [b7] all v2 planes ready

    // ---- B2-GEMM2 (waves 6-7, all 5 mm) + dense o2 stores ----
    if (wid >= 6) {
        float o2a[5][2][4];
        PRIO_HI();
        #pragma unroll
        for (int mm = 0; mm < 5; ++mm) {
            f32x4 accA = {0.f,0.f,0.f,0.f}, accB = {0.f,0.f,0.f,0.f};
            #pragma unroll
            for (int k = 0; k < 3; ++k) {
                short8 au0 = *(const short8*)(ubuf2 + mm * UB2_PLANE + m * UB2_STRIDE + k * 32 + bq * 8);
                short8 au1 = *(const short8*)(ubuf2 + mm * UB2_PLANE + (16 + m) * UB2_STRIDE + k * 32 + bq * 8);
                accA = MFMA(au0, v2f[k], accA);
                accB = MFMA(au1, v2f[k], accB);
            }
            #pragma unroll
            for (int t = 0; t < 2; ++t) {
                f32x4 acc = t ? accB : accA;
                #pragma unroll
                for (int r = 0; r < 4; ++r)
                    o2a[mm][t][r] = acc[r] * yv[t][r];
            }
        }
        PRIO_LO();
        const int jc = (wid - 6) * 16 + m;
        #pragma unroll
        for (int t = 0; t < 2; ++t)
            #pragma unroll
            for (int r = 0; r < 4; ++r) {
                float* p = out + (size_t)(n0 + t * 16 + bq * 4 + r) * 480 + 320 + jc * 5;
                p[0] = o2a[0][t][r]; p[1] = o2a[1][t][r]; p[2] = o2a[2][t][r];
                p[3] = o2a[3][t][r]; p[4] = o2a[4][t][r];
            }
    }
}

extern "C" void kernel_launch(void* const* d_in, const int* in_sizes, int n_in,
                              void* d_out, int out_size, void* d_ws, size_t ws_size,
                              hipStream_t stream)
{
    const float* X   = (const float*)d_in[0];
    const float* Y   = (const float*)d_in[1];
    const float* W0s = (const float*)d_in[2];
    const float* bs  = (const float*)d_in[3];
    const float* W0g = (const float*)d_in[4];
    const float* bg  = (const float*)d_in[5];
    const float* W1  = (const float*)d_in[6];
    const float* W2  = (const float*)d_in[7];
    const float* V0  = (const float*)d_in[8];
    const float* bo  = (const float*)d_in[9];
    const float* V1  = (const float*)d_in[10];
    const float* V2  = (const float*)d_in[11];
    short* WP  = (short*)d_ws;           // 331776 B of bf16-packed weights
    float* out = (float*)d_out;

    const int n = in_sizes[0] / 480;     // 200000
    const int tiles = n / 32;            // 6250 32-node tiles (exact)

    prep_weights<<<dim3((WP_TOTAL + 255) / 256), dim3(256), 0, stream>>>(
        W0s, W0g, W1, W2, V0, V1, V2, WP);
    ffn_main<<<dim3(tiles), dim3(512), 0, stream>>>(X, Y, bs, bg, bo, WP, out);
}

// Round 18
// 313.782 us; speedup vs baseline: 1.0039x; 1.0039x over previous
//
#include <hip/hip_runtime.h>

// ---------------------------------------------------------------------------
// Fused equivariant FFN, bf16 MFMA (16x16x32), fp32 accumulate.
// FINAL (lock-in of Round 16, session best: 314.6us, absmax 0.015625).
// Ladder: 874 -> 664 -> 334 -> 328 -> 323 -> 314.6 us.
//   - 32 nodes/block, 8 waves, 2 row-tiles/wave (MFMA:B-load = 2:1)
//   - weights pre-packed bf16 + INV_* folded (prep_weights, d_ws)
//   - Phase-A depth-2 weight prefetch; all B-phase weights prefetched
//     behind barriers and reused
//   - vectorized LDS staging (short4/short8); transposed gT gate buffer
//   - per-mm ubuf planes -> B-phase barriers batched (19 -> 7)
//   - o1/o2 register-accumulated across mm -> dense 12B/20B stores
// Proven-dead levers (do not revisit): launch_bounds (512,6) [spills to
// 40 VGPR, 2x]; X-register hoisting across Phase A [miscompiles, 2x];
// mm-row-batching / wave-rebalance / ping-pong pipeline [regressions];
// s_setprio [neutral]. Kernel is barrier-chain latency-bound at 2 blocks/CU;
// no saturated pipe (HBM 21%, MFMA 12%, VALU 29%).
// ---------------------------------------------------------------------------

typedef __attribute__((ext_vector_type(8))) short short8;   // 8 bf16 = 4 VGPRs
typedef __attribute__((ext_vector_type(4))) float f32x4;

#define INV_M0f 0.08838834764831845f   // 1/sqrt(128)
#define INV_M1f 0.125f                 // 1/sqrt(64)
#define INV_M2f 0.17677669529663687f   // 1/sqrt(32)
#define INV_H0f 0.05103103630798288f   // 1/sqrt(384)
#define INV_H1f 0.07216878364870323f   // 1/sqrt(192)
#define INV_H2f 0.10206207261596577f   // 1/sqrt(96)

// packed bf16 weight offsets inside d_ws (units: shorts), pre-scaled by INV_*
#define OFF_W0T 0         // [672][128]  (W0s|W0g)^T * INV_M0
#define OFF_W1T 86016     // [192][64]   W1^T * INV_M1
#define OFF_W2T 98304     // [96][32]    W2^T * INV_M2
#define OFF_V0T 101376    // [128][384]  V0^T * INV_H0
#define OFF_V1T 150528    // [64][192]   V1^T * INV_H1
#define OFF_V2T 162816    // [32][96]    V2^T * INV_H2
#define WP_TOTAL 165888

__device__ __forceinline__ short f2bf_rne(float f) {        // prep only
    union { float f; unsigned u; } v; v.f = f;
    unsigned r = v.u + 0x7FFFu + ((v.u >> 16) & 1u);
    return (short)(r >> 16);
}
// 1-VALU bf16 convert (RNE) for the hot kernel
__device__ __forceinline__ short f2bf_fast(float f) {
    unsigned r;
    asm("v_cvt_pk_bf16_f32 %0, %1, %1" : "=v"(r) : "v"(f));
    return (short)r;
}
__device__ __forceinline__ float bf2f(short s) {
    union { unsigned u; float f; } v; v.u = ((unsigned)(unsigned short)s) << 16;
    return v.f;
}

__global__ void prep_weights(const float* __restrict__ W0s, const float* __restrict__ W0g,
                             const float* __restrict__ W1,  const float* __restrict__ W2,
                             const float* __restrict__ V0,  const float* __restrict__ V1,
                             const float* __restrict__ V2,  short* __restrict__ ws)
{
    int i = blockIdx.x * 256 + threadIdx.x;
    if (i < 86016) {                    // W0T [672][128]
        int j = i >> 7, k = i & 127;
        float v = (j < 384) ? W0s[k * 384 + j] : W0g[k * 288 + (j - 384)];
        ws[i] = f2bf_rne(v * INV_M0f);
    } else if (i < 98304) {             // W1T [192][64]
        int e = i - 86016; int w = e >> 6, u = e & 63;
        ws[i] = f2bf_rne(W1[u * 192 + w] * INV_M1f);
    } else if (i < 101376) {            // W2T [96][32]
        int e = i - 98304; int w = e >> 5, u = e & 31;
        ws[i] = f2bf_rne(W2[u * 96 + w] * INV_M2f);
    } else if (i < 150528) {            // V0T [128][384]
        int e = i - 101376; int j = e / 384, w = e % 384;
        ws[i] = f2bf_rne(V0[w * 128 + j] * INV_H0f);
    } else if (i < 162816) {            // V1T [64][192]
        int e = i - 150528; int j = e / 192, w = e % 192;
        ws[i] = f2bf_rne(V1[w * 64 + j] * INV_H1f);
    } else if (i < WP_TOTAL) {          // V2T [32][96]
        int e = i - 162816; int j = e / 96, w = e % 96;
        ws[i] = f2bf_rne(V2[w * 32 + j] * INV_H2f);
    }
}

// ---- LDS layout (shorts), total 36480 shorts = 72960 B ----
// x0s   @     0 : [32][136] = 4352     (start -> end Phase A)
// sbuf  @  4352 : [32][392] = 12544    (Phase A -> Phase D)  [4352,16896)
// gT    @ 26112 : [288][36] = 10368    (Phase A -> end)      [26112,36480)
// x1T   @     0 : [3][32][72] = 6912   (after D; dead x0s+sbuf head)
// ubuf1 @  6912 : [3][32][200] = 19200 (B1 planes)           [6912,26112)
// x2T   @     0 : [5][32][40] = 6400   (staged during B1-G2; dead x1T)
// ubuf2 @  6400 : [5][32][104] = 16640 (B2 planes)           [6400,23040)
#define X0_STRIDE 136
#define SB_OFF 4352
#define SB_STRIDE 392
#define GT_OFF 26112
#define GT_STRIDE 36
#define UB1_OFF 6912
#define UB1_PLANE 6400
#define UB1_STRIDE 200
#define UB2_OFF 6400
#define UB2_PLANE 3328
#define UB2_STRIDE 104
#define LDS_SHORTS 36480

#define MFMA(a, b, c) __builtin_amdgcn_mfma_f32_16x16x32_bf16((a), (b), (c), 0, 0, 0)

__global__ __launch_bounds__(512, 4) void ffn_main(
    const float* __restrict__ X, const float* __restrict__ Y,
    const float* __restrict__ bs, const float* __restrict__ bg, const float* __restrict__ bo,
    const short* __restrict__ WP, float* __restrict__ out)
{
    __shared__ short lds[LDS_SHORTS];
    short* x0s   = lds;
    short* sbuf  = lds + SB_OFF;
    short* gT    = lds + GT_OFF;
    short* x1T   = lds;
    short* x2T   = lds;
    short* ubuf1 = lds + UB1_OFF;
    short* ubuf2 = lds + UB2_OFF;

    const int tid  = threadIdx.x;
    const int wid  = tid >> 6;     // wave 0..7
    const int lane = tid & 63;
    const int m    = lane & 15;    // A-row(node) / B-row(out-col) index
    const int bq   = lane >> 4;    // k-block; D row-group
    const int n0   = blockIdx.x * 32;

    // ---- prefetch Phase-A weight tiles 0 and 1 (depth-2 pipeline) ----
    short8 w0c[4], w0n[4];
    float bias_c, bias_n;
    {
        const short* w = WP + OFF_W0T + (wid * 16 + m) * 128 + bq * 8;
        #pragma unroll
        for (int k = 0; k < 4; ++k) w0c[k] = *(const short8*)(w + k * 32);
        bias_c = bs[wid * 16 + m];
        const short* w2 = WP + OFF_W0T + ((wid + 8) * 16 + m) * 128 + bq * 8;
        #pragma unroll
        for (int k = 0; k < 4; ++k) w0n[k] = *(const short8*)(w2 + k * 32);
        bias_n = bs[(wid + 8) * 16 + m];
    }

    // ---- stage x0 (32 nodes x 128 cols) -> LDS bf16, coalesced ----
    {
        const int node = tid >> 4, c16 = tid & 15;
        const float* xp = X + (size_t)(n0 + node) * 480 + c16 * 8;
        float4 f0 = *(const float4*)xp;
        float4 f1 = *(const float4*)(xp + 4);
        short8 a;
        a[0]=f2bf_fast(f0.x); a[1]=f2bf_fast(f0.y); a[2]=f2bf_fast(f0.z); a[3]=f2bf_fast(f0.w);
        a[4]=f2bf_fast(f1.x); a[5]=f2bf_fast(f1.y); a[6]=f2bf_fast(f1.z); a[7]=f2bf_fast(f1.w);
        *(short8*)(x0s + node * X0_STRIDE + c16 * 8) = a;
    }

    // y for the 8 output rows this lane touches: rows t*16 + bq*4 + r
    float yv[2][4];
    #pragma unroll
    for (int t = 0; t < 2; ++t)
        #pragma unroll
        for (int r = 0; r < 4; ++r)
            yv[t][r] = Y[n0 + t * 16 + bq * 4 + r];

    __syncthreads();                                        // [b1]

    // x0 A-fragments, both row-tiles
    short8 a0[2][4];
    #pragma unroll
    for (int t = 0; t < 2; ++t)
        #pragma unroll
        for (int k = 0; k < 4; ++k)
            a0[t][k] = *(const short8*)(x0s + (t * 16 + m) * X0_STRIDE + k * 32 + bq * 8);

    // ---- Phase A: pre(32x672) = x0 @ W0T^T ; s -> sbuf, g -> gT ----
    // jt = wid + 8i, depth-2 software pipeline (tile i+2 in flight)
    #pragma unroll 1
    for (int i = 0; i < 6; ++i) {
        const int jt = wid + i * 8;
        if (jt >= 42) break;
        const int jnn = jt + 16;
        short8 w0nn[4];
        float bias_nn = 0.f;
        if (jnn < 42) {
            const short* w = WP + OFF_W0T + (jnn * 16 + m) * 128 + bq * 8;
            #pragma unroll
            for (int k = 0; k < 4; ++k) w0nn[k] = *(const short8*)(w + k * 32);
            bias_nn = (jnn < 24) ? bs[jnn * 16 + m] : bg[(jnn - 24) * 16 + m];
        }
        f32x4 acc0 = {0.f,0.f,0.f,0.f}, acc1 = {0.f,0.f,0.f,0.f};
        #pragma unroll
        for (int k = 0; k < 4; ++k) {
            acc0 = MFMA(a0[0][k], w0c[k], acc0);
            acc1 = MFMA(a0[1][k], w0c[k], acc1);
        }
        if (jt < 24) {          // silu -> sbuf, col j = jt*16+m
            #pragma unroll
            for (int t = 0; t < 2; ++t) {
                f32x4 acc = t ? acc1 : acc0;
                #pragma unroll
                for (int r = 0; r < 4; ++r) {
                    float val = fmaf(acc[r], yv[t][r], bias_c);
                    float e   = __expf(-val);
                    float sv  = val * __builtin_amdgcn_rcpf(1.f + e);
                    sbuf[(t * 16 + bq * 4 + r) * SB_STRIDE + jt * 16 + m] = f2bf_fast(sv);
                }
            }
        } else {                // sigmoid -> gT[w][node], short4 over r
            const int w = (jt - 24) * 16 + m;
            #pragma unroll
            for (int t = 0; t < 2; ++t) {
                f32x4 acc = t ? acc1 : acc0;
                float sg[4];
                #pragma unroll
                for (int r = 0; r < 4; ++r) {
                    float val = fmaf(acc[r], yv[t][r], bias_c);
                    float e   = __expf(-val);
                    sg[r] = __builtin_amdgcn_rcpf(1.f + e);
                }
                short4 pk;
                pk.x = f2bf_fast(sg[0]); pk.y = f2bf_fast(sg[1]);
                pk.z = f2bf_fast(sg[2]); pk.w = f2bf_fast(sg[3]);
                *(short4*)(gT + w * GT_STRIDE + t * 16 + bq * 4) = pk;
            }
        }
        #pragma unroll
        for (int k = 0; k < 4; ++k) { w0c[k] = w0n[k]; w0n[k] = w0nn[k]; }
        bias_c = bias_n;
        bias_n = bias_nn;
    }

    // ---- prefetch Phase-D weights (V0T) + bias before the barrier ----
    short8 v0f[12];
    {
        const short* v = WP + OFF_V0T + (wid * 16 + m) * 384 + bq * 8;
        #pragma unroll
        for (int k = 0; k < 12; ++k) v0f[k] = *(const short8*)(v + k * 32);
    }
    const float bo_r = bo[wid * 16 + m];
    __syncthreads();                                        // [b2]

    // ---- Phase D: o0(32x128) = s @ V0 ; 1 j-tile per wave ----
    {
        f32x4 accD0 = {0.f,0.f,0.f,0.f}, accD1 = {0.f,0.f,0.f,0.f};
        #pragma unroll
        for (int k = 0; k < 12; ++k) {
            short8 sa0 = *(const short8*)(sbuf + m * SB_STRIDE + k * 32 + bq * 8);
            short8 sa1 = *(const short8*)(sbuf + (16 + m) * SB_STRIDE + k * 32 + bq * 8);
            accD0 = MFMA(sa0, v0f[k], accD0);
            accD1 = MFMA(sa1, v0f[k], accD1);
        }
        #pragma unroll
        for (int t = 0; t < 2; ++t) {
            f32x4 acc = t ? accD1 : accD0;
            #pragma unroll
            for (int r = 0; r < 4; ++r)
                out[(size_t)(n0 + t * 16 + bq * 4 + r) * 480 + wid * 16 + m] =
                    fmaf(acc[r], yv[t][r], bo_r);
        }
    }

    // ---- prefetch B1 + B2 weights while D's sbuf reads drain ----
    short8 w1f[2][2];                   // [jj][k4], jt = wid + jj*8 (<12)
    #pragma unroll
    for (int jj = 0; jj < 2; ++jj) {
        const int jt = wid + jj * 8;
        if (jt < 12) {
            const short* w = WP + OFF_W1T + (jt * 16 + m) * 64 + bq * 8;
            w1f[jj][0] = *(const short8*)(w);
            w1f[jj][1] = *(const short8*)(w + 32);
        }
    }
    short8 v1f[6];                      // waves 4..7: V1T j-tile (wid-4)
    if (wid >= 4) {
        const short* v = WP + OFF_V1T + ((wid - 4) * 16 + m) * 192 + bq * 8;
        #pragma unroll
        for (int k = 0; k < 6; ++k) v1f[k] = *(const short8*)(v + k * 32);
    }
    short8 w2f;                          // waves 0..5: W2T j-tile wid
    if (wid < 6)
        w2f = *(const short8*)(WP + OFF_W2T + (wid * 16 + m) * 32 + bq * 8);
    short8 v2f[3];                       // waves 6..7: V2T j-tile (wid-6)
    if (wid >= 6) {
        const short* v = WP + OFF_V2T + ((wid - 6) * 16 + m) * 96 + bq * 8;
        #pragma unroll
        for (int k = 0; k < 3; ++k) v2f[k] = *(const short8*)(v + k * 32);
    }
    __syncthreads();   // [b3] sbuf reads done; x1T region may be written

    // ---- stage x1 transposed: x1T[mm][node][u]; short4-wide writes ----
    {
        const int node = tid >> 4, c16 = tid & 15;
        const float* xp = X + (size_t)(n0 + node) * 480 + 128 + c16 * 12;
        float4 fa = *(const float4*)xp;
        float4 fb = *(const float4*)(xp + 4);
        float4 fc = *(const float4*)(xp + 8);
        float vals[12] = {fa.x,fa.y,fa.z,fa.w, fb.x,fb.y,fb.z,fb.w, fc.x,fc.y,fc.z,fc.w};
        #pragma unroll
        for (int mmv = 0; mmv < 3; ++mmv) {
            short4 s4;
            s4.x = f2bf_fast(vals[mmv]);
            s4.y = f2bf_fast(vals[mmv + 3]);
            s4.z = f2bf_fast(vals[mmv + 6]);
            s4.w = f2bf_fast(vals[mmv + 9]);
            *(short4*)(x1T + mmv * 2304 + node * 72 + c16 * 4) = s4;
        }
    }
    __syncthreads();                                        // [b4]

    // ---- B1-GEMM1, ALL 3 mm back-to-back into per-mm planes ----
    #pragma unroll
    for (int mm = 0; mm < 3; ++mm) {
        #pragma unroll
        for (int jj = 0; jj < 2; ++jj) {
            const int jt = wid + jj * 8;
            if (jt < 12) {
                f32x4 accA = {0.f,0.f,0.f,0.f}, accB = {0.f,0.f,0.f,0.f};
                short8 a00 = *(const short8*)(x1T + mm * 2304 + m * 72 + bq * 8);
                short8 a01 = *(const short8*)(x1T + mm * 2304 + m * 72 + 32 + bq * 8);
                short8 a10 = *(const short8*)(x1T + mm * 2304 + (16 + m) * 72 + bq * 8);
                short8 a11 = *(const short8*)(x1T + mm * 2304 + (16 + m) * 72 + 32 + bq * 8);
                accA = MFMA(a00, w1f[jj][0], accA);
                accA = MFMA(a01, w1f[jj][1], accA);
                accB = MFMA(a10, w1f[jj][0], accB);
                accB = MFMA(a11, w1f[jj][1], accB);
                const int w = jt * 16 + m;
                #pragma unroll
                for (int t = 0; t < 2; ++t) {
                    f32x4 acc = t ? accB : accA;
                    short4 g4 = *(const short4*)(gT + w * GT_STRIDE + t * 16 + bq * 4);
                    #pragma unroll
                    for (int r = 0; r < 4; ++r) {
                        const int node = t * 16 + bq * 4 + r;
                        float gv = bf2f(r == 0 ? g4.x : r == 1 ? g4.y : r == 2 ? g4.z : g4.w);
                        ubuf1[mm * UB1_PLANE + node * UB1_STRIDE + w] =
                            f2bf_fast(acc[r] * yv[t][r] * gv);
                    }
                }
            }
        }
    }
    __syncthreads();   // [b5] all v1 planes ready; x1T dead

    // ---- B1-GEMM2 (waves 4-7, all 3 mm) || x2T staging (waves 0-3) ----
    if (wid >= 4) {
        float o1a[3][2][4];
        #pragma unroll
        for (int mm = 0; mm < 3; ++mm) {
            f32x4 accA = {0.f,0.f,0.f,0.f}, accB = {0.f,0.f,0.f,0.f};
            #pragma unroll
            for (int k = 0; k < 6; ++k) {
                short8 au0 = *(const short8*)(ubuf1 + mm * UB1_PLANE + m * UB1_STRIDE + k * 32 + bq * 8);
                short8 au1 = *(const short8*)(ubuf1 + mm * UB1_PLANE + (16 + m) * UB1_STRIDE + k * 32 + bq * 8);
                accA = MFMA(au0, v1f[k], accA);
                accB = MFMA(au1, v1f[k], accB);
            }
            #pragma unroll
            for (int t = 0; t < 2; ++t) {
                f32x4 acc = t ? accB : accA;
                #pragma unroll
                for (int r = 0; r < 4; ++r)
                    o1a[mm][t][r] = acc[r] * yv[t][r];
            }
        }
        // dense o1 stores: 12B contiguous per lane per row
        const int jc = (wid - 4) * 16 + m;
        #pragma unroll
        for (int t = 0; t < 2; ++t)
            #pragma unroll
            for (int r = 0; r < 4; ++r) {
                float* p = out + (size_t)(n0 + t * 16 + bq * 4 + r) * 480 + 128 + jc * 3;
                p[0] = o1a[0][t][r]; p[1] = o1a[1][t][r]; p[2] = o1a[2][t][r];
            }
    } else {
        // x2T [mm][node][u] staged by 256 threads: node = tid>>3, 20 cols each
        const int node2 = tid >> 3;          // 0..31
        const int c8 = tid & 7;
        const float* xp2 = X + (size_t)(n0 + node2) * 480 + 320 + c8 * 20;
        float vals[20];
        #pragma unroll
        for (int p = 0; p < 5; ++p) {
            float4 f = *(const float4*)(xp2 + p * 4);
            vals[p * 4] = f.x; vals[p * 4 + 1] = f.y;
            vals[p * 4 + 2] = f.z; vals[p * 4 + 3] = f.w;
        }
        // col = c8*20 + c -> mm = c%5, u = c8*4 + c/5 ; per mm 4 consecutive u
        #pragma unroll
        for (int mmv = 0; mmv < 5; ++mmv) {
            short4 s4;
            s4.x = f2bf_fast(vals[mmv]);
            s4.y = f2bf_fast(vals[mmv + 5]);
            s4.z = f2bf_fast(vals[mmv + 10]);
            s4.w = f2bf_fast(vals[mmv + 15]);
            *(short4*)(x2T + mmv * 1280 + node2 * 40 + c8 * 4) = s4;
        }
    }
    __syncthreads();   // [b6] x2T ready; ubuf1 reads done (ubuf2 overlays it)

    // ---- B2-GEMM1, ALL 5 mm back-to-back into per-mm planes (waves 0-5) ----
    if (wid < 6) {
        #pragma unroll
        for (int mm = 0; mm < 5; ++mm) {
            f32x4 zz = {0.f,0.f,0.f,0.f};
            short8 a20 = *(const short8*)(x2T + mm * 1280 + m * 40 + bq * 8);
            short8 a21 = *(const short8*)(x2T + mm * 1280 + (16 + m) * 40 + bq * 8);
            f32x4 accA = MFMA(a20, w2f, zz);
            f32x4 accB = MFMA(a21, w2f, zz);
            const int w = 192 + wid * 16 + m;
            #pragma unroll
            for (int t = 0; t < 2; ++t) {
                f32x4 acc = t ? accB : accA;
                short4 g4 = *(const short4*)(gT + w * GT_STRIDE + t * 16 + bq * 4);
                #pragma unroll
                for (int r = 0; r < 4; ++r) {
                    const int node = t * 16 + bq * 4 + r;
                    float gv = bf2f(r == 0 ? g4.x : r == 1 ? g4.y : r == 2 ? g4.z : g4.w);
                    ubuf2[mm * UB2_PLANE + node * UB2_STRIDE + wid * 16 + m] =
                        f2bf_fast(acc[r] * yv[t][r] * gv);
                }
            }
        }
    }
    __syncthreads();   // [b7] all v2 planes ready

    // ---- B2-GEMM2 (waves 6-7, all 5 mm) + dense o2 stores ----
    if (wid >= 6) {
        float o2a[5][2][4];
        #pragma unroll
        for (int mm = 0; mm < 5; ++mm) {
            f32x4 accA = {0.f,0.f,0.f,0.f}, accB = {0.f,0.f,0.f,0.f};
            #pragma unroll
            for (int k = 0; k < 3; ++k) {
                short8 au0 = *(const short8*)(ubuf2 + mm * UB2_PLANE + m * UB2_STRIDE + k * 32 + bq * 8);
                short8 au1 = *(const short8*)(ubuf2 + mm * UB2_PLANE + (16 + m) * UB2_STRIDE + k * 32 + bq * 8);
                accA = MFMA(au0, v2f[k], accA);
                accB = MFMA(au1, v2f[k], accB);
            }
            #pragma unroll
            for (int t = 0; t < 2; ++t) {
                f32x4 acc = t ? accB : accA;
                #pragma unroll
                for (int r = 0; r < 4; ++r)
                    o2a[mm][t][r] = acc[r] * yv[t][r];
            }
        }
        const int jc = (wid - 6) * 16 + m;
        #pragma unroll
        for (int t = 0; t < 2; ++t)
            #pragma unroll
            for (int r = 0; r < 4; ++r) {
                float* p = out + (size_t)(n0 + t * 16 + bq * 4 + r) * 480 + 320 + jc * 5;
                p[0] = o2a[0][t][r]; p[1] = o2a[1][t][r]; p[2] = o2a[2][t][r];
                p[3] = o2a[3][t][r]; p[4] = o2a[4][t][r];
            }
    }
}

extern "C" void kernel_launch(void* const* d_in, const int* in_sizes, int n_in,
                              void* d_out, int out_size, void* d_ws, size_t ws_size,
                              hipStream_t stream)
{
    const float* X   = (const float*)d_in[0];
    const float* Y   = (const float*)d_in[1];
    const float* W0s = (const float*)d_in[2];
    const float* bs  = (const float*)d_in[3];
    const float* W0g = (const float*)d_in[4];
    const float* bg  = (const float*)d_in[5];
    const float* W1  = (const float*)d_in[6];
    const float* W2  = (const float*)d_in[7];
    const float* V0  = (const float*)d_in[8];
    const float* bo  = (const float*)d_in[9];
    const float* V1  = (const float*)d_in[10];
    const float* V2  = (const float*)d_in[11];
    short* WP  = (short*)d_ws;           // 331776 B of bf16-packed weights
    float* out = (float*)d_out;

    const int n = in_sizes[0] / 480;     // 200000
    const int tiles = n / 32;            // 6250 32-node tiles (exact)

    prep_weights<<<dim3((WP_TOTAL + 255) / 256), dim3(256), 0, stream>>>(
        W0s, W0g, W1, W2, V0, V1, V2, WP);
    ffn_main<<<dim3(tiles), dim3(512), 0, stream>>>(X, Y, bs, bg, bo, WP, out);
}